// Round 5
// baseline (232.482 us; speedup 1.0000x reference)
//
#include <hip/hip_runtime.h>

#define T_MAX 512
#define BATCH 32
#define CLASSES 1296
#define L_MAX 64
#define NROWS (T_MAX * BATCH)   // 16384
#define NINF (-INFINITY)
#define NSEQBLK (NROWS / 8)     // 2048
#define NPREDBLK (NROWS / 8)    // 2048

// DPP wave64 sum: row_shr 1/2/4/8 + row_bcast 15/31. Total lands in LANE 63.
__device__ __forceinline__ float wave_sum64(float v) {
    v += __int_as_float(__builtin_amdgcn_update_dpp(0, __float_as_int(v), 0x111, 0xF, 0xF, true));
    v += __int_as_float(__builtin_amdgcn_update_dpp(0, __float_as_int(v), 0x112, 0xF, 0xF, true));
    v += __int_as_float(__builtin_amdgcn_update_dpp(0, __float_as_int(v), 0x114, 0xF, 0xF, true));
    v += __int_as_float(__builtin_amdgcn_update_dpp(0, __float_as_int(v), 0x118, 0xF, 0xF, true));
    v += __int_as_float(__builtin_amdgcn_update_dpp(0, __float_as_int(v), 0x142, 0xF, 0xF, true));
    v += __int_as_float(__builtin_amdgcn_update_dpp(0, __float_as_int(v), 0x143, 0xF, 0xF, true));
    return v;
}

// ---------------------------------------------------------------------------
// K1: ALL streaming in one full-chip burst (128 MB), no align waves competing.
//   blocks 0..2047    : seq rowstats -> lse_seq, + pb staging (row->LDS,
//                       label gather, coalesced 256-B pb row of raw logits --
//                       the DP is invariant to the log-softmax shift).
//   blocks 2048..4095 : pred rowstats -> lse_pred, sum_pred.
// Kernel boundary publishes pb/stats (round 3: per-wave release atomics are
// 5x worse than the boundary's single implicit flush).
// ---------------------------------------------------------------------------
__global__ __launch_bounds__(512, 4) void stream_kernel(
    const float* __restrict__ pred, const float* __restrict__ seqp,
    const int* __restrict__ label,
    float* __restrict__ lse_pred, float* __restrict__ sum_pred,
    float* __restrict__ lse_seq, float* __restrict__ pb,
    int* __restrict__ counter)
{
    __shared__ float rowbuf[8][CLASSES];   // 41.5 KB, seq path only
    const int w = threadIdx.x >> 6, lane = threadIdx.x & 63;
    if (blockIdx.x == 0 && threadIdx.x == 0) *counter = 0;

    if (blockIdx.x < NSEQBLK) {
        // ---------------- seq rowstats + pb staging: one wave per row --------
        const int r = (blockIdx.x << 3) + w;           // [0, NROWS)
        const int b = r & 31, t = r >> 5;
        const float* xs = seqp + (size_t)r * CLASSES;
        const float4* s4 = (const float4*)xs;

        float4 b0 = s4[lane],       b1 = s4[lane + 64],  b2 = s4[lane + 128];
        float4 b3 = s4[lane + 192], b4 = s4[lane + 256];
        float4 bt = make_float4(0.f, 0.f, 0.f, 0.f);
        if (lane < 4) bt = s4[320 + lane];
        const int lab = label[(b << 6) + lane];

        // stage the row to LDS for the label gather (single wave, no barrier)
        float4* rb4 = (float4*)rowbuf[w];
        rb4[lane] = b0; rb4[lane + 64] = b1; rb4[lane + 128] = b2;
        rb4[lane + 192] = b3; rb4[lane + 256] = b4;
        if (lane < 4) rb4[320 + lane] = bt;

        float ss = __expf(b0.x) + __expf(b0.y) + __expf(b0.z) + __expf(b0.w)
                 + __expf(b1.x) + __expf(b1.y) + __expf(b1.z) + __expf(b1.w)
                 + __expf(b2.x) + __expf(b2.y) + __expf(b2.z) + __expf(b2.w)
                 + __expf(b3.x) + __expf(b3.y) + __expf(b3.z) + __expf(b3.w)
                 + __expf(b4.x) + __expf(b4.y) + __expf(b4.z) + __expf(b4.w);
        if (lane < 4)
            ss += __expf(bt.x) + __expf(bt.y) + __expf(bt.z) + __expf(bt.w);
        ss = wave_sum64(ss);
        if (lane == 63) lse_seq[r] = __logf(ss);

        // pb row: raw logit at each label entry, coalesced 256-B store
        pb[(((size_t)(b << 9) + t) << 6) + lane] = rowbuf[w][lab];
    } else {
        // ---------------- pred rowstats: one wave per row ----------------
        const int r = ((blockIdx.x - NSEQBLK) << 3) + w;
        const float* xp = pred + (size_t)r * CLASSES;
        const float4* p4 = (const float4*)xp;

        float4 a0 = p4[lane],       a1 = p4[lane + 64],  a2 = p4[lane + 128];
        float4 a3 = p4[lane + 192], a4 = p4[lane + 256];
        float4 at = make_float4(0.f, 0.f, 0.f, 0.f);
        if (lane < 4) at = p4[320 + lane];

        float sp = __expf(a0.x) + __expf(a0.y) + __expf(a0.z) + __expf(a0.w)
                 + __expf(a1.x) + __expf(a1.y) + __expf(a1.z) + __expf(a1.w)
                 + __expf(a2.x) + __expf(a2.y) + __expf(a2.z) + __expf(a2.w)
                 + __expf(a3.x) + __expf(a3.y) + __expf(a3.z) + __expf(a3.w)
                 + __expf(a4.x) + __expf(a4.y) + __expf(a4.z) + __expf(a4.w);
        float sx = (a0.x + a0.y + a0.z + a0.w) + (a1.x + a1.y + a1.z + a1.w)
                 + (a2.x + a2.y + a2.z + a2.w) + (a3.x + a3.y + a3.z + a3.w)
                 + (a4.x + a4.y + a4.z + a4.w);
        if (lane < 4) {
            sp += __expf(at.x) + __expf(at.y) + __expf(at.z) + __expf(at.w);
            sx += at.x + at.y + at.z + at.w;
        }
        sp = wave_sum64(sp);
        sx = wave_sum64(sx);
        if (lane == 63) {
            lse_pred[r] = __logf(sp);
            sum_pred[r] = sx;
        }
    }
}

// ---------------------------------------------------------------------------
// K2: align DP + fused CE on a quiet chip. 4 blocks x 8 waves = 32 chains
// (2 chains/SIMD interleave dependent-DPP bubbles). Depth-4 register
// prefetch: pb loads issue 3 groups (~1000+ cy) ahead of use, so the
// uncongested L2/L3 latency (~300-600 cy) is fully hidden -- rounds 0/4
// only prefetched 1 group (~320 cy) and exposed latency on every group.
// After backtrack, each block computes CE for its own 8 batches (rows_s is
// block-local), removing the separate ce_kernel and the tg round-trip.
// ---------------------------------------------------------------------------
__global__ __launch_bounds__(512, 2) void align_ce_kernel(
    const float* __restrict__ pred, const float* __restrict__ pb,
    const int* __restrict__ label, const int* __restrict__ x_len,
    const int* __restrict__ label_len,
    const float* __restrict__ lse_pred, const float* __restrict__ sum_pred,
    const float* __restrict__ lse_seq,
    float* __restrict__ partials, int* __restrict__ counter,
    float* __restrict__ out)
{
    __shared__ unsigned chw[8][1024];   // per-wave choice bits [panel][lane] (32 KB)
    __shared__ int a_s[8][64];
    __shared__ int rows_s[8][T_MAX];
    __shared__ float sm[8];
    const int w = threadIdx.x >> 6, lane = threadIdx.x & 63;

    const int b = (blockIdx.x << 3) + w;
    const int C = x_len[b], R = label_len[b];
    const int limit = C - R;
    const float* pbb = pb + ((size_t)b << 15);     // b * 512 * 64
    const int P = (C + 31) >> 5;                   // panels of 32 cols, in [8,16]
    const int G = P << 1;                          // groups of 16 cols (even)
    const float biasR = (lane < R) ? 0.f : NINF;
    const bool isb0 = (lane & 15) == 0;
    const int ninf_i = 0xFF800000;
    unsigned* chwl = chw[w];

    float bA[16], bB[16], bC[16], bD[16];
    float dp = NINF;
    unsigned w0 = 0;

#define GLOAD(VV, GG) {                                                        \
        int gi_ = (GG); if (gi_ > G - 1) gi_ = G - 1;                          \
        const float* s_ = pbb + ((size_t)gi_ << 10);                           \
        _Pragma("unroll")                                                      \
        for (int u = 0; u < 16; ++u) VV[u] = s_[(u << 6) + lane];              \
    }

#define COMPUTE16(VV, GG) {                                                    \
        const int g_ = (GG);                                                   \
        const bool general = (g_ < 2) || (((g_ << 4) + 15) > limit);           \
        _Pragma("unroll")                                                      \
        for (int u = 0; u < 16; ++u) {                                         \
            const int j = (g_ << 4) + u;                                       \
            float val;                                                         \
            if (general) {                                                     \
                if (g_ == 0 && u == 0) {            /* column 0 init */        \
                    dp = (lane == 0) ? VV[0] : NINF;                           \
                    continue;                                                  \
                }                                                              \
                const bool ib = (lane <= j) && (lane >= j - limit) && (lane < R); \
                val = ib ? VV[u] : NINF;                                       \
            } else {                                                           \
                val = VV[u] + biasR;                /* off-chain R mask */     \
            }                                                                  \
            const int dpb = __float_as_int(dp);                                \
            const int t1 = __builtin_amdgcn_update_dpp(ninf_i, dpb, 0x111, 0xF, 0xF, false); /* row_shr:1 */ \
            const int t2 = __builtin_amdgcn_update_dpp(ninf_i, dpb, 0x142, 0xF, 0xF, false); /* row_bcast15 */ \
            const float shifted = __int_as_float(isb0 ? t2 : t1);              \
            const bool c = shifted > dp;            /* strict, off chain */    \
            w0 |= (c ? 1u : 0u) << (j & 31);                                   \
            dp = fmaxf(shifted, dp) + val;          /* == reference select */  \
        }                                                                      \
    }

    // prologue: 3 groups in flight (G >= 16 always since C >= 256)
    GLOAD(bA, 0) GLOAD(bB, 1) GLOAD(bC, 2)
    for (int g = 0; g < G; g += 4) {
        GLOAD(bD, g + 3)
        COMPUTE16(bA, g)
        GLOAD(bA, g + 4)
        COMPUTE16(bB, g + 1)
        chwl[((g >> 1) << 6) + lane] = w0; w0 = 0;
        if (g + 2 < G) {
            GLOAD(bB, g + 5)
            COMPUTE16(bC, g + 2)
            GLOAD(bC, g + 6)
            COMPUTE16(bD, g + 3)
            chwl[(((g >> 1) + 1) << 6) + lane] = w0; w0 = 0;
        }
    }
#undef GLOAD
#undef COMPUTE16

    // backtrack: per-row jumps via highest set bit in cached words
    if (lane == 0) {
        int row = R - 1, j = C - 1;
        while (row > 0 && j >= 0) {
            unsigned word = chwl[((j >> 5) << 6) + row];
            unsigned mb = (2u << (j & 31)) - 1;
            unsigned m = word & mb;
            if (m) {
                int hb = 31 - __clz(m);
                int aj = (j & ~31) | hb;
                a_s[w][row] = aj;
                row--; j = aj - 1;
            } else {
                j = (j & ~31) - 1;
            }
        }
        for (int i = row; i >= 0; --i) a_s[w][i] = 0;
    }
    // parallel interval fill: row i occupies [a_s[i], b_i]  (same wave -> no barrier)
    if (lane < R) {
        int a = a_s[w][lane];
        int bi = (lane == R - 1) ? (C - 1) : (a_s[w][lane + 1] - 1);
        for (int j = a; j <= bi; ++j) rows_s[w][j] = lane;
    }

    // ---- fused CE for this wave's batch: 8 elements per lane, high MLP ----
    float ces = 0.f;
    #pragma unroll
    for (int k = 0; k < 8; ++k) {
        const int t = (k << 6) + lane;
        if (t < C) {
            const int e = (t << 5) + b;
            const int row = rows_s[w][t];
            const int tgt = label[(b << 6) + row];
            const float lp = lse_pred[e];
            const float S = sum_pred[e] - (float)CLASSES * lp;   // sum_v log_softmax(pred)
            const float lsp_t = pred[(size_t)e * CLASSES + tgt] - lp;
            const float conf = __expf(pb[(((size_t)(b << 9) + t) << 6) + row] - lse_seq[e]);
            const float smooth = (1.f - conf) * (1.f / (float)(CLASSES - 1));
            ces += -((conf - smooth) * lsp_t + smooth * S);
        }
    }
    ces = wave_sum64(ces);                        // wave total in lane 63
    if (lane == 63) sm[w] = ces;
    __syncthreads();
    if (threadIdx.x == 0) {
        float p = sm[0] + sm[1] + sm[2] + sm[3] + sm[4] + sm[5] + sm[6] + sm[7];
        __hip_atomic_store(&partials[blockIdx.x], p, __ATOMIC_RELEASE, __HIP_MEMORY_SCOPE_AGENT);
        if (__hip_atomic_fetch_add(counter, 1, __ATOMIC_ACQ_REL, __HIP_MEMORY_SCOPE_AGENT) == 3) {
            float v = 0.f;
            for (int i = 0; i < 4; ++i)          // fixed order -> deterministic
                v += __hip_atomic_load(&partials[i], __ATOMIC_ACQUIRE, __HIP_MEMORY_SCOPE_AGENT);
            out[0] = v * (1.0f / (float)NROWS);
        }
    }
}

extern "C" void kernel_launch(void* const* d_in, const int* in_sizes, int n_in,
                              void* d_out, int out_size, void* d_ws, size_t ws_size,
                              hipStream_t stream) {
    const float* pred      = (const float*)d_in[0];
    const float* seq_pred  = (const float*)d_in[1];
    const int*   label     = (const int*)d_in[2];
    const int*   x_len     = (const int*)d_in[3];
    const int*   label_len = (const int*)d_in[4];
    float* out = (float*)d_out;

    // workspace layout (floats)
    float* ws = (float*)d_ws;
    float* lse_pred = ws;                      // 16384
    float* sum_pred = ws + NROWS;              // 16384
    float* lse_seq  = ws + 2 * NROWS;          // 16384
    float* pb       = ws + 3 * NROWS;          // 32*512*64 = 1048576
    float* partials = pb + (size_t)BATCH * T_MAX * 64;  // 4
    int*   counter  = (int*)(partials + 4);    // 1

    stream_kernel<<<NSEQBLK + NPREDBLK, 512, 0, stream>>>(
        pred, seq_pred, label, lse_pred, sum_pred, lse_seq, pb, counter);
    align_ce_kernel<<<4, 512, 0, stream>>>(
        pred, pb, label, x_len, label_len,
        lse_pred, sum_pred, lse_seq, partials, counter, out);
}